// Round 8
// baseline (112.270 us; speedup 1.0000x reference)
//
#include <hip/hip_runtime.h>
#include <cstdint>
#include <cstddef>

// Problem dims
constexpr int Bv = 4096;   // batch
constexpr int Dv = 1024;   // feature dim
constexpr int Cv = 1000;   // classes
constexpr int Tv = 32;     // trees
constexpr int NI = 63;     // internal nodes per tree
constexpr int NL = 64;     // leaves per tree
constexpr int TNp = 2048;  // padded node dim: tree t at cols [64t, 64t+63]
constexpr int TL = Tv * NL;   // 2048
constexpr int Npad = 1024;    // padded class dim

typedef _Float16 h8  __attribute__((ext_vector_type(8)));
typedef _Float16 h4  __attribute__((ext_vector_type(4)));
typedef short    s8v __attribute__((ext_vector_type(8)));
typedef unsigned short us8 __attribute__((ext_vector_type(8)));
typedef float    f4v __attribute__((ext_vector_type(4)));

// ---------------------------------------------------------------------------
// Workspace layout (float units). Total ~40.5 MB.
// ---------------------------------------------------------------------------
constexpr size_t N_X    = (size_t)Bv * Dv;                 // 4M elems
constexpr size_t N_W    = (size_t)TNp * Dv;                // 2M elems (padded)
constexpr size_t OFF_XH = 64;                              // f16 [Bv][Dv]
constexpr size_t OFF_WH = OFF_XH + N_X / 2;                // f16 [TNp][Dv]
constexpr size_t OFF_P  = OFF_WH + N_W / 2;                // fp32 [TL][Cv]
constexpr size_t OFF_MH = OFF_P + (size_t)TL * Cv;         // bf16 [Bv][TL]
constexpr size_t OFF_PTH= OFF_MH + (size_t)Bv * TL / 2;    // bf16 [Npad][TL]

// bf16 round-to-nearest-even from fp32
__device__ __forceinline__ unsigned short f2bf_rn(float x) {
    unsigned u = __float_as_uint(x);
    return (unsigned short)((u + 0x7fffu + ((u >> 16) & 1u)) >> 16);
}

// async global->LDS, 16B per lane, LDS dest = wave-uniform base + lane*16
__device__ __forceinline__ void gll16(const void* gptr, void* lptr) {
    __builtin_amdgcn_global_load_lds(
        (const __attribute__((address_space(1))) unsigned int*)gptr,
        (__attribute__((address_space(3))) unsigned int*)lptr,
        16, 0, 0);
}

// ---------------------------------------------------------------------------
// Kernel A (grid-sectioned, all sections independent):
//   blocks [0, 4096)        : x fp32 -> Xh f16
//   blocks [4096, 6144)     : W re-pack rows (t*63+i)->(t*64+i), f16, pad 0
//   blocks [6144, 8192)     : leaf softmax row -> fp32 P
// ---------------------------------------------------------------------------
__global__ __launch_bounds__(256)
void k_prep_leaf(const float* __restrict__ x, const float* __restrict__ sw,
                 const float* __restrict__ ll, const float* __restrict__ lt,
                 _Float16* __restrict__ Xh, _Float16* __restrict__ Wh,
                 float* __restrict__ P) {
    const int b = blockIdx.x;
    const int tid = threadIdx.x;
    if (b < 4096) {
        const size_t i4 = ((size_t)b * 256 + tid) * 4;
        const float4 v = *reinterpret_cast<const float4*>(&x[i4]);
        h4 vh;
        vh[0] = (_Float16)v.x; vh[1] = (_Float16)v.y;
        vh[2] = (_Float16)v.z; vh[3] = (_Float16)v.w;
        *reinterpret_cast<h4*>(&Xh[i4]) = vh;
    } else if (b < 6144) {
        const size_t d4 = ((size_t)(b - 4096) * 256 + tid) * 4;
        const int row = (int)(d4 >> 10);
        const int col = (int)(d4 & 1023);
        const int t = row >> 6, i = row & 63;
        float4 v = make_float4(0.f, 0.f, 0.f, 0.f);
        if (i < NI)
            v = *reinterpret_cast<const float4*>(&sw[(size_t)(t * NI + i) * Dv + col]);
        h4 vh;
        vh[0] = (_Float16)v.x; vh[1] = (_Float16)v.y;
        vh[2] = (_Float16)v.z; vh[3] = (_Float16)v.w;
        *reinterpret_cast<h4*>(&Wh[d4]) = vh;
    } else {
        const int r = b - 6144;
        const float temp = fminf(fmaxf(expf(lt[0]), 0.1f), 5.0f);
        const float invT = 1.0f / temp;
        const float* row = ll + (size_t)r * Cv;
        float* pr = P + (size_t)r * Cv;
        __shared__ float redm[4];
        __shared__ float reds[4];

        float m = -3.4e38f;
        for (int c = tid; c < Cv; c += 256) m = fmaxf(m, row[c] * invT);
        #pragma unroll
        for (int o = 32; o > 0; o >>= 1) m = fmaxf(m, __shfl_down(m, o));
        if ((tid & 63) == 0) redm[tid >> 6] = m;
        __syncthreads();
        m = fmaxf(fmaxf(redm[0], redm[1]), fmaxf(redm[2], redm[3]));

        float sum = 0.f;
        for (int c = tid; c < Cv; c += 256) {
            const float e = expf(row[c] * invT - m);
            pr[c] = e;
            sum += e;
        }
        #pragma unroll
        for (int o = 32; o > 0; o >>= 1) sum += __shfl_down(sum, o);
        if ((tid & 63) == 0) reds[tid >> 6] = sum;
        __syncthreads();
        sum = reds[0] + reds[1] + reds[2] + reds[3];
        const float rs = 1.0f / sum;
        for (int c = tid; c < Cv; c += 256) pr[c] *= rs;
    }
}

// ---------------------------------------------------------------------------
// Kernel B (grid-sectioned):
//   blocks [0, 512)    : GEMM1+mu fused. 128x128 tile, BK=64, 4 waves 2x2.
//                        A (X) via global_load_lds dbuf; B (W) direct
//                        global->VGPR dbuf (removes B from LDS: 44 FLOP/B).
//   blocks [512, 1024) : transpose P fp32 [TL][Cv] -> PTH bf16 [Npad][TL]
// ---------------------------------------------------------------------------
__global__ __launch_bounds__(256, 2)
void k_gemm1mu_tp(const _Float16* __restrict__ Xh, const _Float16* __restrict__ Wh,
                  const float* __restrict__ bias, const float* __restrict__ tw,
                  const float* __restrict__ lt, const float* __restrict__ P,
                  unsigned short* __restrict__ MH, unsigned short* __restrict__ PTH) {
    // staging: 2 bufs x (A 128x64 f16 = 16KB) = 32KB; epilogue scratch
    // 4 waves x [64][65] f32 = 66,560 B (union, used after the K-loop)
    __shared__ __align__(16) char lds[4 * 64 * 65 * 4];

    const int tid = threadIdx.x;

    if (blockIdx.x >= 512) {
        // ---------------- transpose-P section ----------------
        const int tpb = blockIdx.x - 512;
        const int k0 = (tpb & 31) * 64;
        const int c0 = (tpb >> 5) * 64;
        float* T = (float*)lds;   // [64][65]
        #pragma unroll
        for (int i = 0; i < 16; ++i) {
            const int idx = tid + i * 256;
            const int kk = idx >> 6, cc = idx & 63;
            const int c = c0 + cc;
            T[kk * 65 + cc] = (c < Cv) ? P[(size_t)(k0 + kk) * Cv + c] : 0.f;
        }
        __syncthreads();
        #pragma unroll
        for (int i = 0; i < 16; ++i) {
            const int idx = tid + i * 256;
            const int cc = idx >> 6, kk = idx & 63;
            PTH[(size_t)(c0 + cc) * TL + k0 + kk] = f2bf_rn(T[kk * 65 + cc]);
        }
        return;
    }

    // ---------------- GEMM1+mu section ----------------
    // XCD swizzle: 512 wgs, 8 chunks of 64 = 16(by) x 4(bx) sub-blocks
    const int wg  = (blockIdx.x & 7) * 64 + (blockIdx.x >> 3);
    const int blk = wg >> 6;
    const int j   = wg & 63;
    const int bx  = (blk & 3) * 4 + (j & 3);       // 0..15
    const int by  = (blk >> 2) * 16 + (j >> 2);    // 0..31
    const int bm = by * 128, bn = bx * 128;

    const int lane = tid & 63, wv = tid >> 6;
    const int wr = wv >> 1, wc = wv & 1;
    const int lrow = lane & 15, kg = (lane >> 4) * 8;
    const int sr = lane >> 3;            // staging row within 8-row chunk
    const int sc = (lane & 7) * 8;       // staging f16 col (0..56)

    // scalars inline
    const float temp = fminf(fmaxf(expf(lt[0]), 0.1f), 5.0f);
    const float invT = 1.0f / temp;
    const int mytree = 2 * bx + wc;
    float wm = -3.4e38f;
    #pragma unroll
    for (int t = 0; t < Tv; ++t) wm = fmaxf(wm, tw[t]);
    float wsum = 0.f, wmine = 0.f;
    #pragma unroll
    for (int t = 0; t < Tv; ++t) {
        const float e = expf(tw[t] - wm);
        wsum += e;
        if (t == mytree) wmine = e;
    }
    const float wt = wmine / wsum;

    f4v acc[4][4] = {};
    h8 breg0[4][2], breg1[4][2];

    // A slab 128x64 f16 = 16KB = 16 chunks of 1KB (8 rows each); 4/wave
#define STG_A(bufi, k0)                                                       \
    { _Pragma("unroll")                                                       \
      for (int i_ = 0; i_ < 4; ++i_) {                                        \
        const int ch_  = wv * 4 + i_;                                         \
        const int row_ = ch_ * 8 + sr;                                        \
        gll16(&Xh[(size_t)(bm + row_) * Dv + (k0) + sc],                      \
              lds + (bufi) * 16384 + ch_ * 1024);                             \
      } }

    // B (weights) direct global->VGPR: 4nf x 2kh = 8 x 16B loads per iter
#define BLOAD1(dst, k0)                                                       \
    { _Pragma("unroll")                                                       \
      for (int nf_ = 0; nf_ < 4; ++nf_) {                                     \
        _Pragma("unroll")                                                     \
        for (int kh_ = 0; kh_ < 2; ++kh_) {                                   \
          dst[nf_][kh_] = *reinterpret_cast<const h8*>(                       \
              &Wh[(size_t)(bn + wc * 64 + nf_ * 16 + lrow) * Dv +             \
                  (k0) + kh_ * 32 + kg]);                                     \
        } } }

    // per-wave vmem ops per iter = 4 (gload_lds) + 8 (B loads) = 12
#define ITER1(T, CBUF, CURB, NBUF, NXTB, LAST)                                \
  {                                                                           \
    if (!(LAST)) {                                                            \
      STG_A(NBUF, ((T) + 1) * 64);                                            \
      BLOAD1(NXTB, ((T) + 1) * 64);                                           \
      __builtin_amdgcn_sched_barrier(0);                                      \
      asm volatile("s_waitcnt vmcnt(12)" ::: "memory");                       \
    } else {                                                                  \
      asm volatile("s_waitcnt vmcnt(0)" ::: "memory");                        \
    }                                                                         \
    __builtin_amdgcn_s_barrier();                                             \
    __builtin_amdgcn_sched_barrier(0);                                        \
    _Pragma("unroll")                                                         \
    for (int kh = 0; kh < 2; ++kh) {                                          \
      h8 a_[4];                                                               \
      _Pragma("unroll")                                                       \
      for (int mf = 0; mf < 4; ++mf)                                          \
        a_[mf] = *reinterpret_cast<const h8*>(                                \
            lds + (CBUF) * 16384 +                                            \
            ((wr * 64 + mf * 16 + lrow) * 64 + kh * 32 + kg) * 2);            \
      _Pragma("unroll")                                                       \
      for (int mf = 0; mf < 4; ++mf)                                          \
        _Pragma("unroll")                                                     \
        for (int nf = 0; nf < 4; ++nf)                                        \
          acc[mf][nf] = __builtin_amdgcn_mfma_f32_16x16x32_f16(               \
              a_[mf], CURB[nf][kh], acc[mf][nf], 0, 0, 0);                    \
    }                                                                         \
    __builtin_amdgcn_sched_barrier(0);                                        \
    asm volatile("s_waitcnt lgkmcnt(0)" ::: "memory");                        \
    __builtin_amdgcn_s_barrier();                                             \
  }

    STG_A(0, 0);
    BLOAD1(breg0, 0);
    for (int tt = 0; tt < 7; ++tt) {
        ITER1(2 * tt,     0, breg0, 1, breg1, false);
        ITER1(2 * tt + 1, 1, breg1, 0, breg0, false);
    }
    ITER1(14, 0, breg0, 1, breg1, false);
    ITER1(15, 1, breg1, 0, breg0, true);
#undef ITER1
#undef BLOAD1
#undef STG_A

    // ---- epilogue: sigmoid -> per-wave [64 rows][65] f32 scratch ----
    float* scr = (float*)lds + wv * (64 * 65);
    #pragma unroll
    for (int nf = 0; nf < 4; ++nf) {
        const int colB = nf * 16 + lrow;                 // node idx 0..63
        const int gcol = bn + wc * 64 + colB;
        const int ii = gcol & 63;
        const float bv = (ii < NI) ? bias[(gcol >> 6) * NI + ii] : 0.f;
        #pragma unroll
        for (int mf = 0; mf < 4; ++mf) {
            #pragma unroll
            for (int r = 0; r < 4; ++r) {
                const int rowB = mf * 16 + (lane >> 4) * 4 + r;
                const float z = (acc[mf][nf][r] + bv) * invT;
                scr[rowB * 65 + colB] = 1.0f / (1.0f + __expf(-z));
            }
        }
    }
    asm volatile("s_waitcnt lgkmcnt(0)" ::: "memory");   // wave-local writes done

    // ---- per-lane mu: row = lane, tree = mytree ----
    const float* srow = scr + lane * 65;
    float mu[NL];
    mu[0] = wt;
    #pragma unroll
    for (int d = 0; d < 6; ++d) {
        const int width = 1 << d;
        #pragma unroll
        for (int i = width - 1; i >= 0; --i) {
            const float sv = srow[width - 1 + i];
            const float m  = mu[i];
            mu[2 * i + 1] = m * sv;
            mu[2 * i]     = m * (1.0f - sv);
        }
    }
    const size_t obase = (size_t)(bm + wr * 64 + lane) * TL + (size_t)mytree * 64;
    #pragma unroll
    for (int c = 0; c < 8; ++c) {
        us8 vh;
        #pragma unroll
        for (int jj = 0; jj < 8; ++jj) vh[jj] = f2bf_rn(mu[c * 8 + jj]);
        *reinterpret_cast<us8*>(&MH[obase + c * 8]) = vh;
    }
}

// ---------------------------------------------------------------------------
// GEMM2 (single-pass bf16): out = muw @ P. A = MH [Bv][TL], B = PTH [Npad][TL].
// 128x64 tile, 2 waves (128 threads) each 64x64 -> 33 FLOP/LDS-byte.
// A via global_load_lds dbuf; B direct global->VGPR dbuf. BK=64, 32 iters.
// Grid 512, 4 blocks/CU. XCD swizzle 8 chunks of 64 = 8(bn) x 8(bm).
// ---------------------------------------------------------------------------
__global__ __launch_bounds__(128, 2)
void k_gemm2(const unsigned short* __restrict__ MH, const unsigned short* __restrict__ PTH,
             float* __restrict__ out) {
    __shared__ __align__(16) char lds[2 * 16384];   // 2 bufs x A 128x64 bf16

    const int tid  = threadIdx.x;
    const int wg  = (blockIdx.x & 7) * 64 + (blockIdx.x >> 3);
    const int blk = wg >> 6;                        // 0..7
    const int j   = wg & 63;
    const int bnt = (blk & 1) * 8 + (j & 7);        // 0..15
    const int bmt = (blk >> 1) * 8 + (j >> 3);      // 0..31
    const int bm = bmt * 128, bn = bnt * 64;

    const int lane = tid & 63;
    const int wv   = tid >> 6;           // 0..1 (row half)
    const int lrow = lane & 15;
    const int kg   = (lane >> 4) * 8;
    const int sr   = lane >> 3;          // staging row within 8-row chunk
    const int sc   = (lane & 7) * 8;     // staging bf16 col

    f4v acc[4][4] = {};
    s8v breg0[4][2], breg1[4][2];

    // A slab 128x64 bf16 = 16KB = 16 chunks; 8 per wave
#define STG2(bufi, k0)                                                        \
    { _Pragma("unroll")                                                       \
      for (int i_ = 0; i_ < 8; ++i_) {                                        \
        const int ch_  = wv * 8 + i_;                                         \
        const int row_ = ch_ * 8 + sr;                                        \
        gll16(&MH[(size_t)(bm + row_) * TL + (k0) + sc],                      \
              lds + (bufi) * 16384 + ch_ * 1024);                             \
      } }

#define BLOAD2(dst, k0)                                                       \
    { _Pragma("unroll")                                                       \
      for (int nf_ = 0; nf_ < 4; ++nf_) {                                     \
        _Pragma("unroll")                                                     \
        for (int kh_ = 0; kh_ < 2; ++kh_) {                                   \
          dst[nf_][kh_] = *reinterpret_cast<const s8v*>(                      \
              &PTH[(size_t)(bn + nf_ * 16 + lrow) * TL +                      \
                   (k0) + kh_ * 32 + kg]);                                    \
        } } }

    // per-wave vmem ops per iter = 8 (gload_lds) + 8 (B loads) = 16
#define ITER2(T, CBUF, CURB, NBUF, NXTB, LAST)                                \
  {                                                                           \
    if (!(LAST)) {                                                            \
      STG2(NBUF, ((T) + 1) * 64);                                             \
      BLOAD2(NXTB, ((T) + 1) * 64);                                           \
      __builtin_amdgcn_sched_barrier(0);                                      \
      asm volatile("s_waitcnt vmcnt(16)" ::: "memory");                       \
    } else {                                                                  \
      asm volatile("s_waitcnt vmcnt(0)" ::: "memory");                        \
    }                                                                         \
    __builtin_amdgcn_s_barrier();                                             \
    __builtin_amdgcn_sched_barrier(0);                                        \
    _Pragma("unroll")                                                         \
    for (int kh = 0; kh < 2; ++kh) {                                          \
      s8v a_[4];                                                              \
      _Pragma("unroll")                                                       \
      for (int mf = 0; mf < 4; ++mf)                                          \
        a_[mf] = *reinterpret_cast<const s8v*>(                               \
            lds + (CBUF) * 16384 +                                            \
            ((wv * 64 + mf * 16 + lrow) * 64 + kh * 32 + kg) * 2);            \
      _Pragma("unroll")                                                       \
      for (int mf = 0; mf < 4; ++mf)                                          \
        _Pragma("unroll")                                                     \
        for (int nf = 0; nf < 4; ++nf)                                        \
          acc[mf][nf] = __builtin_amdgcn_mfma_f32_16x16x32_bf16(              \
              a_[mf], CURB[nf][kh], acc[mf][nf], 0, 0, 0);                    \
    }                                                                         \
    __builtin_amdgcn_sched_barrier(0);                                        \
    asm volatile("s_waitcnt lgkmcnt(0)" ::: "memory");                        \
    __builtin_amdgcn_s_barrier();                                             \
  }

    STG2(0, 0);
    BLOAD2(breg0, 0);
    for (int tt = 0; tt < 15; ++tt) {
        ITER2(2 * tt,     0, breg0, 1, breg1, false);
        ITER2(2 * tt + 1, 1, breg1, 0, breg0, false);
    }
    ITER2(30, 0, breg0, 1, breg1, false);
    ITER2(31, 1, breg1, 0, breg0, true);
#undef ITER2
#undef BLOAD2
#undef STG2

    #pragma unroll
    for (int nf = 0; nf < 4; ++nf) {
        const int col = bn + nf * 16 + lrow;
        if (col >= Cv) continue;
        #pragma unroll
        for (int mf = 0; mf < 4; ++mf) {
            #pragma unroll
            for (int r = 0; r < 4; ++r) {
                const int row = bm + wv * 64 + mf * 16 + (lane >> 4) * 4 + r;
                out[(size_t)row * Cv + col] = acc[mf][nf][r];
            }
        }
    }
}

// ---------------------------------------------------------------------------
extern "C" void kernel_launch(void* const* d_in, const int* in_sizes, int n_in,
                              void* d_out, int out_size, void* d_ws, size_t ws_size,
                              hipStream_t stream) {
    const float* x  = (const float*)d_in[0];  // [B, D]
    const float* sw = (const float*)d_in[1];  // [T, NI, D]
    const float* sb = (const float*)d_in[2];  // [T, NI]
    const float* ll = (const float*)d_in[3];  // [T, NL, C]
    const float* tw = (const float*)d_in[4];  // [T]
    const float* lt = (const float*)d_in[5];  // scalar

    float* out  = (float*)d_out;              // [B, C]
    float* ws   = (float*)d_ws;
    _Float16* Xh = (_Float16*)(ws + OFF_XH);
    _Float16* Wh = (_Float16*)(ws + OFF_WH);
    float* Pbuf = ws + OFF_P;
    unsigned short* MH  = (unsigned short*)(ws + OFF_MH);
    unsigned short* PTH = (unsigned short*)(ws + OFF_PTH);

    k_prep_leaf<<<8192, 256, 0, stream>>>(x, sw, ll, lt, Xh, Wh, Pbuf);
    k_gemm1mu_tp<<<1024, 256, 0, stream>>>(Xh, Wh, sb, tw, lt, Pbuf, MH, PTH);
    k_gemm2<<<512, 128, 0, stream>>>(MH, PTH, out);
}

// Round 9
// 82.506 us; speedup vs baseline: 1.3608x; 1.3608x over previous
//
#include <hip/hip_runtime.h>
#include <cstdint>
#include <cstddef>

// Problem dims
constexpr int Bv = 4096;   // batch
constexpr int Dv = 1024;   // feature dim
constexpr int Cv = 1000;   // classes
constexpr int Tv = 32;     // trees
constexpr int NI = 63;     // internal nodes per tree
constexpr int NL = 64;     // leaves per tree
constexpr int TNp = 2048;  // padded node dim: tree t at cols [64t, 64t+63]
constexpr int TL = Tv * NL;   // 2048
constexpr int Npad = 1024;    // padded class dim

typedef _Float16 h8  __attribute__((ext_vector_type(8)));
typedef _Float16 h4  __attribute__((ext_vector_type(4)));
typedef short    s8v __attribute__((ext_vector_type(8)));
typedef unsigned short us8 __attribute__((ext_vector_type(8)));
typedef float    f4v __attribute__((ext_vector_type(4)));

// ---------------------------------------------------------------------------
// Workspace layout (float units). Total ~40.5 MB.
// ---------------------------------------------------------------------------
constexpr size_t N_X    = (size_t)Bv * Dv;                 // 4M elems
constexpr size_t N_W    = (size_t)TNp * Dv;                // 2M elems (padded)
constexpr size_t OFF_XH = 64;                              // f16 [Bv][Dv]
constexpr size_t OFF_WH = OFF_XH + N_X / 2;                // f16 [TNp][Dv]
constexpr size_t OFF_P  = OFF_WH + N_W / 2;                // fp32 [TL][Cv]
constexpr size_t OFF_MH = OFF_P + (size_t)TL * Cv;         // bf16 [Bv][TL]
constexpr size_t OFF_PTH= OFF_MH + (size_t)Bv * TL / 2;    // bf16 [Npad][TL]

// bf16 round-to-nearest-even from fp32
__device__ __forceinline__ unsigned short f2bf_rn(float x) {
    unsigned u = __float_as_uint(x);
    return (unsigned short)((u + 0x7fffu + ((u >> 16) & 1u)) >> 16);
}

// async global->LDS, 16B per lane, LDS dest = wave-uniform base + lane*16
__device__ __forceinline__ void gll16(const void* gptr, void* lptr) {
    __builtin_amdgcn_global_load_lds(
        (const __attribute__((address_space(1))) unsigned int*)gptr,
        (__attribute__((address_space(3))) unsigned int*)lptr,
        16, 0, 0);
}

// ---------------------------------------------------------------------------
// Kernel A (grid-sectioned, all sections independent):
//   blocks [0, 4096)        : x fp32 -> Xh f16
//   blocks [4096, 6144)     : W re-pack rows (t*63+i)->(t*64+i), f16, pad 0
//   blocks [6144, 8192)     : leaf softmax row -> fp32 P
// ---------------------------------------------------------------------------
__global__ __launch_bounds__(256)
void k_prep_leaf(const float* __restrict__ x, const float* __restrict__ sw,
                 const float* __restrict__ ll, const float* __restrict__ lt,
                 _Float16* __restrict__ Xh, _Float16* __restrict__ Wh,
                 float* __restrict__ P) {
    const int b = blockIdx.x;
    const int tid = threadIdx.x;
    if (b < 4096) {
        const size_t i4 = ((size_t)b * 256 + tid) * 4;
        const float4 v = *reinterpret_cast<const float4*>(&x[i4]);
        h4 vh;
        vh[0] = (_Float16)v.x; vh[1] = (_Float16)v.y;
        vh[2] = (_Float16)v.z; vh[3] = (_Float16)v.w;
        *reinterpret_cast<h4*>(&Xh[i4]) = vh;
    } else if (b < 6144) {
        const size_t d4 = ((size_t)(b - 4096) * 256 + tid) * 4;
        const int row = (int)(d4 >> 10);
        const int col = (int)(d4 & 1023);
        const int t = row >> 6, i = row & 63;
        float4 v = make_float4(0.f, 0.f, 0.f, 0.f);
        if (i < NI)
            v = *reinterpret_cast<const float4*>(&sw[(size_t)(t * NI + i) * Dv + col]);
        h4 vh;
        vh[0] = (_Float16)v.x; vh[1] = (_Float16)v.y;
        vh[2] = (_Float16)v.z; vh[3] = (_Float16)v.w;
        *reinterpret_cast<h4*>(&Wh[d4]) = vh;
    } else {
        const int r = b - 6144;
        const float temp = fminf(fmaxf(expf(lt[0]), 0.1f), 5.0f);
        const float invT = 1.0f / temp;
        const float* row = ll + (size_t)r * Cv;
        float* pr = P + (size_t)r * Cv;
        __shared__ float redm[4];
        __shared__ float reds[4];

        float m = -3.4e38f;
        for (int c = tid; c < Cv; c += 256) m = fmaxf(m, row[c] * invT);
        #pragma unroll
        for (int o = 32; o > 0; o >>= 1) m = fmaxf(m, __shfl_down(m, o));
        if ((tid & 63) == 0) redm[tid >> 6] = m;
        __syncthreads();
        m = fmaxf(fmaxf(redm[0], redm[1]), fmaxf(redm[2], redm[3]));

        float sum = 0.f;
        for (int c = tid; c < Cv; c += 256) {
            const float e = expf(row[c] * invT - m);
            pr[c] = e;
            sum += e;
        }
        #pragma unroll
        for (int o = 32; o > 0; o >>= 1) sum += __shfl_down(sum, o);
        if ((tid & 63) == 0) reds[tid >> 6] = sum;
        __syncthreads();
        sum = reds[0] + reds[1] + reds[2] + reds[3];
        const float rs = 1.0f / sum;
        for (int c = tid; c < Cv; c += 256) pr[c] *= rs;
    }
}

// ---------------------------------------------------------------------------
// Kernel B (grid-sectioned):
//   blocks [0, 512)    : GEMM1+mu fused. 128x128 tile, BK=32, 4 waves 2x2,
//                        both operands via global_load_lds dbuf, counted
//                        vmcnt(4). Epilogue sigmoid stored as f16 in LDS
//                        scratch (33.3 KB union -> 4 blocks/CU, 16 waves/CU).
//   blocks [512, 1024) : transpose P fp32 [TL][Cv] -> PTH bf16 [Npad][TL]
// ---------------------------------------------------------------------------
__global__ __launch_bounds__(256, 4)
void k_gemm1mu_tp(const _Float16* __restrict__ Xh, const _Float16* __restrict__ Wh,
                  const float* __restrict__ bias, const float* __restrict__ tw,
                  const float* __restrict__ lt, const float* __restrict__ P,
                  unsigned short* __restrict__ MH, unsigned short* __restrict__ PTH) {
    // union: staging 2 bufs x (X 8KB + W 8KB) = 32 KB;
    // epilogue scratch 4 waves x [64][65] f16 = 33,280 B; tp tile 16,640 B.
    __shared__ __align__(16) char lds[33280];

    const int tid = threadIdx.x;

    if (blockIdx.x >= 512) {
        // ---------------- transpose-P section ----------------
        const int tpb = blockIdx.x - 512;
        const int k0 = (tpb & 31) * 64;
        const int c0 = (tpb >> 5) * 64;
        float* T = (float*)lds;   // [64][65]
        #pragma unroll
        for (int i = 0; i < 16; ++i) {
            const int idx = tid + i * 256;
            const int kk = idx >> 6, cc = idx & 63;
            const int c = c0 + cc;
            T[kk * 65 + cc] = (c < Cv) ? P[(size_t)(k0 + kk) * Cv + c] : 0.f;
        }
        __syncthreads();
        #pragma unroll
        for (int i = 0; i < 16; ++i) {
            const int idx = tid + i * 256;
            const int cc = idx >> 6, kk = idx & 63;
            PTH[(size_t)(c0 + cc) * TL + k0 + kk] = f2bf_rn(T[kk * 65 + cc]);
        }
        return;
    }

    // ---------------- GEMM1+mu section ----------------
    // XCD swizzle: 512 wgs, 8 chunks of 64 = 16(by) x 4(bx) sub-blocks
    const int wg  = (blockIdx.x & 7) * 64 + (blockIdx.x >> 3);
    const int blk = wg >> 6;
    const int j   = wg & 63;
    const int bx  = (blk & 3) * 4 + (j & 3);       // 0..15
    const int by  = (blk >> 2) * 16 + (j >> 2);    // 0..31
    const int bm = by * 128, bn = bx * 128;

    const int lane = tid & 63, wv = tid >> 6;
    const int wr = wv >> 1, wc = wv & 1;
    const int lrow = lane & 15, kg = (lane >> 4) * 8;
    const int sr = lane >> 2;            // staging row within 16-row chunk
    const int sc = (lane & 3) * 8;       // staging f16 col (0,8,16,24)

    // scalars inline
    const float temp = fminf(fmaxf(expf(lt[0]), 0.1f), 5.0f);
    const float invT = 1.0f / temp;
    const int mytree = 2 * bx + wc;
    float wm = -3.4e38f;
    #pragma unroll
    for (int t = 0; t < Tv; ++t) wm = fmaxf(wm, tw[t]);
    float wsum = 0.f, wmine = 0.f;
    #pragma unroll
    for (int t = 0; t < Tv; ++t) {
        const float e = expf(tw[t] - wm);
        wsum += e;
        if (t == mytree) wmine = e;
    }
    const float wt = wmine / wsum;

    f4v acc[4][4] = {};

    // BK=32: slab 128x32 f16 = 8KB = 8 chunks of 1KB (16 rows each);
    // 2 chunks/wave/slab -> 4 gll16 issues per wave per tile
#define STG(bufi, k0)                                                         \
    { _Pragma("unroll")                                                       \
      for (int i_ = 0; i_ < 2; ++i_) {                                        \
        const int ch_  = wv * 2 + i_;                                         \
        const int row_ = ch_ * 16 + sr;                                       \
        gll16(&Xh[(size_t)(bm + row_) * Dv + (k0) + sc],                      \
              lds + (bufi) * 16384 + ch_ * 1024);                             \
        gll16(&Wh[(size_t)(bn + row_) * Dv + (k0) + sc],                      \
              lds + (bufi) * 16384 + 8192 + ch_ * 1024);                      \
      } }

    STG(0, 0);
    for (int t = 0; t < 32; ++t) {
        const int cur = t & 1;
        if (t < 31) {
            STG(cur ^ 1, (t + 1) * 32);
            asm volatile("s_waitcnt vmcnt(4)" ::: "memory");  // current tile's 4 done
        } else {
            asm volatile("s_waitcnt vmcnt(0)" ::: "memory");
        }
        __builtin_amdgcn_s_barrier();
        __builtin_amdgcn_sched_barrier(0);

        h8 a[4], b[4];
        #pragma unroll
        for (int mf = 0; mf < 4; ++mf)
            a[mf] = *reinterpret_cast<const h8*>(
                lds + cur * 16384 + ((wr * 64 + mf * 16 + lrow) * 32 + kg) * 2);
        #pragma unroll
        for (int nf = 0; nf < 4; ++nf)
            b[nf] = *reinterpret_cast<const h8*>(
                lds + cur * 16384 + 8192 + ((wc * 64 + nf * 16 + lrow) * 32 + kg) * 2);
        #pragma unroll
        for (int mf = 0; mf < 4; ++mf)
            #pragma unroll
            for (int nf = 0; nf < 4; ++nf)
                acc[mf][nf] = __builtin_amdgcn_mfma_f32_16x16x32_f16(a[mf], b[nf], acc[mf][nf], 0, 0, 0);

        __builtin_amdgcn_sched_barrier(0);
        asm volatile("s_waitcnt lgkmcnt(0)" ::: "memory");
        __builtin_amdgcn_s_barrier();   // safe to overwrite cur next iter
    }
#undef STG

    // ---- epilogue: sigmoid -> per-wave [64 rows][65] f16 scratch ----
    _Float16* scr = (_Float16*)lds + wv * (64 * 65);
    #pragma unroll
    for (int nf = 0; nf < 4; ++nf) {
        const int colB = nf * 16 + lrow;                 // node idx 0..63
        const int gcol = bn + wc * 64 + colB;
        const int ii = gcol & 63;
        const float bv = (ii < NI) ? bias[(gcol >> 6) * NI + ii] : 0.f;
        #pragma unroll
        for (int mf = 0; mf < 4; ++mf) {
            #pragma unroll
            for (int r = 0; r < 4; ++r) {
                const int rowB = mf * 16 + (lane >> 4) * 4 + r;
                const float z = (acc[mf][nf][r] + bv) * invT;
                scr[rowB * 65 + colB] = (_Float16)(1.0f / (1.0f + __expf(-z)));
            }
        }
    }
    asm volatile("s_waitcnt lgkmcnt(0)" ::: "memory");   // wave-local writes done

    // ---- per-lane mu: row = lane, tree = mytree; s read from f16 LDS ----
    const _Float16* srow = scr + lane * 65;
    float mu[NL];
    mu[0] = wt;
    #pragma unroll
    for (int d = 0; d < 6; ++d) {
        const int width = 1 << d;
        #pragma unroll
        for (int i = width - 1; i >= 0; --i) {
            const float sv = (float)srow[width - 1 + i];
            const float m  = mu[i];
            mu[2 * i + 1] = m * sv;
            mu[2 * i]     = m * (1.0f - sv);
        }
    }
    const size_t obase = (size_t)(bm + wr * 64 + lane) * TL + (size_t)mytree * 64;
    #pragma unroll
    for (int c = 0; c < 8; ++c) {
        us8 vh;
        #pragma unroll
        for (int jj = 0; jj < 8; ++jj) vh[jj] = f2bf_rn(mu[c * 8 + jj]);
        *reinterpret_cast<us8*>(&MH[obase + c * 8]) = vh;
    }
}

// ---------------------------------------------------------------------------
// GEMM2 (single-pass bf16): out = muw @ P. A = MH [Bv][TL], B = PTH [Npad][TL].
// 128x64 tile, K-step 64 (two 32-sub-steps), double-buffered, counted vmcnt.
// XCD swizzle: chunks of 64 = 8(bm) x 8(bn) sub-blocks.  (round-7 proven)
// ---------------------------------------------------------------------------
__global__ __launch_bounds__(256, 2)
void k_gemm2(const unsigned short* __restrict__ MH, const unsigned short* __restrict__ PTH,
             float* __restrict__ out) {
    __shared__ unsigned short LA[2][2][128][32];   // 32 KB
    __shared__ unsigned short LB[2][2][64][32];    // 16 KB

    const int tid  = threadIdx.x;
    const int wg  = (blockIdx.x & 7) * 64 + (blockIdx.x >> 3);
    const int blk = wg >> 6;                        // 0..7
    const int j   = wg & 63;
    const int bnt = (blk & 1) * 8 + (j & 7);        // 0..15
    const int bmt = (blk >> 1) * 8 + (j >> 3);      // 0..31
    const int bm = bmt * 128, bn = bnt * 64;

    const int lane = tid & 63;
    const int wv   = tid >> 6;
    const int wr   = wv >> 1;
    const int wc   = wv & 1;
    const int lrow = lane & 15;
    const int kg   = (lane >> 4) * 8;
    const int sr   = lane >> 2;
    const int sc   = (lane & 3) * 8;

    f4v acc[4][2] = {};

#define STAGE2(bufi, k0)                                                          \
    { _Pragma("unroll")                                                           \
      for (int kh_ = 0; kh_ < 2; ++kh_) {                                         \
        _Pragma("unroll")                                                         \
        for (int i_ = 0; i_ < 2; ++i_) {                                          \
          const int ch_  = wv * 2 + i_;                                           \
          const int row_ = ch_ * 16 + sr;                                         \
          gll16(&MH[(size_t)(bm + row_) * TL + (k0) + kh_ * 32 + sc],             \
                (char*)&LA[bufi][kh_][0][0] + ch_ * 1024);                        \
        }                                                                         \
        { const int row_ = wv * 16 + sr;                                          \
          gll16(&PTH[(size_t)(bn + row_) * TL + (k0) + kh_ * 32 + sc],            \
                (char*)&LB[bufi][kh_][0][0] + wv * 1024); }                       \
      } }

    STAGE2(0, 0);
    for (int t = 0; t < 32; ++t) {
        const int cur = t & 1;
        if (t < 31) {
            STAGE2(cur ^ 1, (t + 1) * 64);
            asm volatile("s_waitcnt vmcnt(6)" ::: "memory");
        } else {
            asm volatile("s_waitcnt vmcnt(0)" ::: "memory");
        }
        __builtin_amdgcn_s_barrier();
        __builtin_amdgcn_sched_barrier(0);

        #pragma unroll
        for (int kh = 0; kh < 2; ++kh) {
            s8v a[4], b[2];
            #pragma unroll
            for (int mf = 0; mf < 4; ++mf)
                a[mf] = *reinterpret_cast<const s8v*>(&LA[cur][kh][wr * 64 + mf * 16 + lrow][kg]);
            #pragma unroll
            for (int nf = 0; nf < 2; ++nf)
                b[nf] = *reinterpret_cast<const s8v*>(&LB[cur][kh][wc * 32 + nf * 16 + lrow][kg]);
            #pragma unroll
            for (int mf = 0; mf < 4; ++mf)
                #pragma unroll
                for (int nf = 0; nf < 2; ++nf)
                    acc[mf][nf] = __builtin_amdgcn_mfma_f32_16x16x32_bf16(a[mf], b[nf], acc[mf][nf], 0, 0, 0);
        }

        __builtin_amdgcn_sched_barrier(0);
        asm volatile("s_waitcnt lgkmcnt(0)" ::: "memory");
        __builtin_amdgcn_s_barrier();
    }
#undef STAGE2

    #pragma unroll
    for (int nf = 0; nf < 2; ++nf) {
        const int col = bn + wc * 32 + nf * 16 + lrow;
        if (col >= Cv) continue;
        #pragma unroll
        for (int mf = 0; mf < 4; ++mf) {
            #pragma unroll
            for (int r = 0; r < 4; ++r) {
                const int row = bm + wr * 64 + mf * 16 + (lane >> 4) * 4 + r;
                out[(size_t)row * Cv + col] = acc[mf][nf][r];
            }
        }
    }
}

// ---------------------------------------------------------------------------
extern "C" void kernel_launch(void* const* d_in, const int* in_sizes, int n_in,
                              void* d_out, int out_size, void* d_ws, size_t ws_size,
                              hipStream_t stream) {
    const float* x  = (const float*)d_in[0];  // [B, D]
    const float* sw = (const float*)d_in[1];  // [T, NI, D]
    const float* sb = (const float*)d_in[2];  // [T, NI]
    const float* ll = (const float*)d_in[3];  // [T, NL, C]
    const float* tw = (const float*)d_in[4];  // [T]
    const float* lt = (const float*)d_in[5];  // scalar

    float* out  = (float*)d_out;              // [B, C]
    float* ws   = (float*)d_ws;
    _Float16* Xh = (_Float16*)(ws + OFF_XH);
    _Float16* Wh = (_Float16*)(ws + OFF_WH);
    float* Pbuf = ws + OFF_P;
    unsigned short* MH  = (unsigned short*)(ws + OFF_MH);
    unsigned short* PTH = (unsigned short*)(ws + OFF_PTH);

    k_prep_leaf<<<8192, 256, 0, stream>>>(x, sw, ll, lt, Xh, Wh, Pbuf);
    k_gemm1mu_tp<<<1024, 256, 0, stream>>>(Xh, Wh, sb, tw, lt, Pbuf, MH, PTH);
    k_gemm2<<<512, 256, 0, stream>>>(MH, PTH, out);
}